// Round 3
// baseline (2980.697 us; speedup 1.0000x reference)
//
#include <hip/hip_runtime.h>
#include <stdint.h>

// ============================================================================
// LSTM (B=2048,T=256,D=32,H=256) + FC(256) on gfx950.
// R7: fully block-local recurrence -- NO cross-block exchange at all.
// 128 blocks (one per batch-tile of 16 rows), 512 thr (8 waves), 1 block/CU.
// Each block computes the ENTIRE hidden state for its 16 rows. Wave w owns
// hidden units w*32..w*32+32 across ALL 4 gates (128 gate-cols): 72 weight
// frags (9 ktiles x 2 hu-tiles x 4 gates) persistent in VGPRs = 288 regs.
// __launch_bounds__(512,1) -> 512-VGPR budget so they stay resident
// (R3 lesson: lower bound demotes weights to scratch).
// Per step: 9 ds_read_b128 (A-frags, shared by 8 MFMAs each) -> 72 MFMA
// -> in-lane activations (C/D col=lane&15 -> hidden unit, row=quad*4+reg ->
// batch row; i,f,g,o for one unit all in the same lane) -> h write to the
// other parity buffer -> ONE __syncthreads per step. WAR-safe: step t reads
// A[p] before the barrier, step t+1 writes A[p] after it.
// R6 post-mortem: any per-step cross-CU round trip costs >=2-4k cycles of
// exposed latency+skew; deleting it beats using twice the CUs.
// MFMA layouts (learn_hip verified): A[m=lane&15][k=(lane>>4)*8+j],
// B^T same, C/D: col=lane&15, row=(lane>>4)*4+reg.
// ============================================================================

typedef __attribute__((ext_vector_type(8))) short short8;
typedef __attribute__((ext_vector_type(4))) float f32x4;

#define LDSTRIDE 296  // 288 K-cols + 8 pad shorts (row stride: 2-way bank alias = free)

__device__ __forceinline__ short f2bf(float f) {
  uint32_t u = __builtin_bit_cast(uint32_t, f);
  u = (u + 0x7FFFu + ((u >> 16) & 1u)) >> 16;  // RNE
  return (short)(uint16_t)u;
}

#define LOG2E 1.4426950408889634f
__device__ __forceinline__ float sigmoidf_(float x) {
  return __builtin_amdgcn_rcpf(1.0f + __builtin_amdgcn_exp2f(-LOG2E * x));
}
__device__ __forceinline__ float tanhf_(float x) {
  float t = __builtin_amdgcn_exp2f((2.0f * LOG2E) * x);
  return 1.0f - 2.0f * __builtin_amdgcn_rcpf(t + 1.0f);
}

// ---------------------------------------------------------------------------
// Pack W_hh[1024x256] (k 0..255) + W_ih[1024x32] (k 256..287) into bf16 frags.
// frag = ((w*9 + kt)*2 + ht)*4 + g ; element (lane,j):
//   n = g*256 + w*32 + ht*16 + (lane&15), k = kt*32 + (lane>>4)*8 + j
// ---------------------------------------------------------------------------
__global__ void pack_w(const float* __restrict__ Whh, const float* __restrict__ Wih,
                       short* __restrict__ wpack) {
  int tid = blockIdx.x * 256 + threadIdx.x;  // 576 frags * 64 lanes
  if (tid >= 576 * 64) return;
  int lane = tid & 63;
  int frag = tid >> 6;
  int g = frag & 3;
  int r1 = frag >> 2;
  int ht = r1 & 1;
  int r2 = r1 >> 1;  // w*9 + kt, 0..71
  int kt = r2 % 9;
  int w = r2 / 9;
  int n = g * 256 + w * 32 + ht * 16 + (lane & 15);
  int k0 = kt * 32 + (lane >> 4) * 8;
  short8 v;
#pragma unroll
  for (int j = 0; j < 8; ++j) {
    int k = k0 + j;
    float f = (k < 256) ? Whh[n * 256 + k] : Wih[n * 32 + (k - 256)];
    v[j] = f2bf(f);
  }
  *(short8*)(wpack + (size_t)frag * 512 + lane * 8) = v;
}

// W_fc[256x256] -> frags (kt 0..7, ct 0..15): n = ct*16+(lane&15).
__global__ void pack_wfc(const float* __restrict__ Wfc, short* __restrict__ wfc) {
  int tid = blockIdx.x * 256 + threadIdx.x;  // 128 frags * 64 lanes
  if (tid >= 128 * 64) return;
  int lane = tid & 63;
  int frag = tid >> 6;
  int ct = frag & 15, kt = frag >> 4;
  int n = ct * 16 + (lane & 15);
  int k0 = kt * 32 + (lane >> 4) * 8;
  short8 v;
#pragma unroll
  for (int j = 0; j < 8; ++j) v[j] = f2bf(Wfc[n * 256 + k0 + j]);
  *(short8*)(wfc + (size_t)frag * 512 + lane * 8) = v;
}

// ---------------------------------------------------------------------------
// Main kernel: grid 128 (one batch-tile each); block 512.
// ---------------------------------------------------------------------------
__global__ __launch_bounds__(512, 1) void lstm_main(
    const float* __restrict__ obs, const short8* __restrict__ wpack,
    const short8* __restrict__ wfc, const float* __restrict__ b_ih,
    const float* __restrict__ b_hh, const float* __restrict__ b_fc,
    float* __restrict__ out) {
  __shared__ __align__(16) short A[2][16 * LDSTRIDE];  // parity double-buffer
  const int tid = threadIdx.x;
  const int w = tid >> 6, lane = tid & 63;
  const int l15 = lane & 15, quad = lane >> 4;
  const int row0 = blockIdx.x * 16;
  const int xr = tid >> 5, xd = tid & 31;  // x staging: row, d

  // zero A[0] (h_0 = 0); A[1] is fully written during step 0
  for (int i = tid; i < 16 * LDSTRIDE; i += 512) A[0][i] = 0;

  // persistent weight registers: 72 frags = 288 VGPRs (constant indices only)
  short8 wfr[9][2][4];
#pragma unroll
  for (int kt = 0; kt < 9; ++kt)
#pragma unroll
    for (int ht = 0; ht < 2; ++ht)
#pragma unroll
      for (int g = 0; g < 4; ++g)
        wfr[kt][ht][g] =
            wpack[(size_t)(((w * 9 + kt) * 2 + ht) * 4 + g) * 64 + lane];

  // fused bias: lane's hidden units are w*32 + ht*16 + l15
  float bias[2][4];
#pragma unroll
  for (int ht = 0; ht < 2; ++ht)
#pragma unroll
    for (int g = 0; g < 4; ++g) {
      int idx = g * 256 + w * 32 + ht * 16 + l15;
      bias[ht][g] = b_ih[idx] + b_hh[idx];
    }

  float c4[2][4];
#pragma unroll
  for (int ht = 0; ht < 2; ++ht)
#pragma unroll
    for (int i = 0; i < 4; ++i) c4[ht][i] = 0.f;

  __syncthreads();  // zeroing done
  A[0][xr * LDSTRIDE + 256 + xd] =
      f2bf(obs[((size_t)(row0 + xr) * 256 + 0) * 32 + xd]);
  __syncthreads();  // x_0 staged

  for (int t = 0; t < 256; ++t) {
    const int p = t & 1;
    short* __restrict__ Acur = &A[p][0];
    short* __restrict__ Anx = &A[p ^ 1][0];
    const int tn = (t < 255) ? (t + 1) : 255;
    // prefetch x_{t+1} (consumed at step end; latency hidden under GEMM)
    const float xv = obs[((size_t)(row0 + xr) * 256 + tn) * 32 + xd];

    // full GEMM: z[16 x 128] for this wave over K=288 (h 0..255, x 256..287)
    f32x4 acc[2][4];
#pragma unroll
    for (int ht = 0; ht < 2; ++ht)
#pragma unroll
      for (int g = 0; g < 4; ++g)
        acc[ht][g] = (f32x4){bias[ht][g], bias[ht][g], bias[ht][g], bias[ht][g]};

#pragma unroll
    for (int kt = 0; kt < 9; ++kt) {
      const short8 a_ = *(const short8*)&Acur[l15 * LDSTRIDE + kt * 32 + quad * 8];
#pragma unroll
      for (int ht = 0; ht < 2; ++ht)
#pragma unroll
        for (int g = 0; g < 4; ++g)
          acc[ht][g] = __builtin_amdgcn_mfma_f32_16x16x32_bf16(
              a_, wfr[kt][ht][g], acc[ht][g], 0, 0, 0);
    }

    // activations (in-lane): rows quad*4+reg, hidden units w*32+ht*16+l15
    short hb[2][4];
#pragma unroll
    for (int ht = 0; ht < 2; ++ht)
#pragma unroll
      for (int reg = 0; reg < 4; ++reg) {
        float iv = sigmoidf_(acc[ht][0][reg]);
        float fv = sigmoidf_(acc[ht][1][reg]);
        float gv = tanhf_(acc[ht][2][reg]);
        float ov = sigmoidf_(acc[ht][3][reg]);
        float cc = fv * c4[ht][reg] + iv * gv;
        c4[ht][reg] = cc;
        hb[ht][reg] = f2bf(ov * tanhf_(cc));
      }

    // h_{t+1} + x_{t+1} into the other parity buffer
#pragma unroll
    for (int ht = 0; ht < 2; ++ht)
#pragma unroll
      for (int reg = 0; reg < 4; ++reg)
        Anx[(quad * 4 + reg) * LDSTRIDE + w * 32 + ht * 16 + l15] = hb[ht][reg];
    Anx[xr * LDSTRIDE + 256 + xd] = f2bf(xv);

    __syncthreads();  // single barrier per step (double-buffer makes WAR safe)
  }

  // FC epilogue: h_256 is in A[0]. Wave w -> cols w*32..+32 (2 col-tiles).
#pragma unroll
  for (int ht = 0; ht < 2; ++ht) {
    const int ct = w * 2 + ht;
    f32x4 ao = (f32x4){0.f, 0.f, 0.f, 0.f};
#pragma unroll
    for (int kt = 0; kt < 8; ++kt) {
      const short8 a = *(const short8*)&A[0][l15 * LDSTRIDE + kt * 32 + quad * 8];
      const short8 b = wfc[(size_t)(kt * 16 + ct) * 64 + lane];
      ao = __builtin_amdgcn_mfma_f32_16x16x32_bf16(a, b, ao, 0, 0, 0);
    }
    const int col = ct * 16 + l15;
    const float bv = b_fc[col];
#pragma unroll
    for (int reg = 0; reg < 4; ++reg) {
      const int row = row0 + quad * 4 + reg;
      out[(size_t)row * 256 + col] = ao[reg] + bv;
    }
  }
}

extern "C" void kernel_launch(void* const* d_in, const int* in_sizes, int n_in,
                              void* d_out, int out_size, void* d_ws, size_t ws_size,
                              hipStream_t stream) {
  const float* obs  = (const float*)d_in[0];   // [2048,256,32]
  const float* W_ih = (const float*)d_in[1];   // [1024,32]
  const float* W_hh = (const float*)d_in[2];   // [1024,256]
  const float* b_ih = (const float*)d_in[3];   // [1024]
  const float* b_hh = (const float*)d_in[4];   // [1024]
  const float* W_fc = (const float*)d_in[5];   // [256,256]
  const float* b_fc = (const float*)d_in[6];   // [256]
  float* out = (float*)d_out;                  // [2048,256]

  // ws layout
  short* wpack = (short*)d_ws;        // 576*512 shorts = 576 KB
  short* wfcp  = wpack + 576 * 512;   // 128*512 shorts = 128 KB

  hipLaunchKernelGGL(pack_w, dim3(144), dim3(256), 0, stream, W_hh, W_ih, wpack);
  hipLaunchKernelGGL(pack_wfc, dim3(32), dim3(256), 0, stream, W_fc, wfcp);
  hipLaunchKernelGGL(lstm_main, dim3(128), dim3(512), 0, stream, obs,
                     (const short8*)wpack, (const short8*)wfcp,
                     b_ih, b_hh, b_fc, out);
}

// Round 4
// 773.893 us; speedup vs baseline: 3.8516x; 3.8516x over previous
//
#include <hip/hip_runtime.h>
#include <stdint.h>

// ============================================================================
// LSTM (B=2048,T=256,D=32,H=256) + FC(256) on gfx950.
// R8 = R6 + lgkm-only barriers (single change, for attribution).
// R6 recap: 256 blocks = 128 batch-tiles x 2 col-groups (pair b <-> b+128,
// same XCD), 512 thr (8 waves), 1 block/CU. Wave w owns hidden units
// cg*128+w*16..+16, all 4 gates; 36 weight frags persistent in VGPRs.
// GEMM split local (own h-half + x, no sibling dep) / remote (sibling half).
// Exchange: two 8B relaxed agent atomics per lane, step tag in bits 63:48
// (|h|<1 -> no aliasing; parity double-buffer + recurrence dep = WAR-safe).
// R8 change: __syncthreads() emits s_waitcnt vmcnt(0) before s_barrier
// (m97 asm evidence), which drains the just-issued slab store's L3 ack
// (~500-1000cy) into every step, twice. The tagged protocol needs only LDS
// visibility across the barrier -> replace both in-loop barriers with
//   asm("s_waitcnt lgkmcnt(0)\n\ts_barrier" ::: "memory")
// so the slab store + obs prefetch stay in flight (T4 counted-wait spirit).
// R7 lesson (VGPR_Count=128, FETCH 1.95GB): 8-wave blocks cap at 256
// VGPR/wave; full 576KB weights can never be single-CU resident -> the
// 2-CU split + exchange is structurally necessary.
// MFMA layouts (learn_hip verified): A[m=lane&15][k=(lane>>4)*8+j],
// B^T same, C/D: col=lane&15, row=(lane>>4)*4+reg.
// ============================================================================

typedef __attribute__((ext_vector_type(8))) short short8;
typedef __attribute__((ext_vector_type(4))) float f32x4;
typedef unsigned long long ull;

#define LDSTRIDE 296  // 288 K-cols + 8 pad shorts
#define NBT 128       // batch tiles

// lgkm-only barrier: LDS visibility across waves WITHOUT draining VMEM.
// Single asm block so no memory op can be scheduled between wait and barrier.
#define BARRIER_LGKM() \
  asm volatile("s_waitcnt lgkmcnt(0)\n\ts_barrier" ::: "memory")

__device__ __forceinline__ short f2bf(float f) {
  uint32_t u = __builtin_bit_cast(uint32_t, f);
  u = (u + 0x7FFFu + ((u >> 16) & 1u)) >> 16;  // RNE
  return (short)(uint16_t)u;
}

#define LOG2E 1.4426950408889634f
__device__ __forceinline__ float sigmoidf_(float x) {
  return __builtin_amdgcn_rcpf(1.0f + __builtin_amdgcn_exp2f(-LOG2E * x));
}
__device__ __forceinline__ float tanhf_(float x) {
  float t = __builtin_amdgcn_exp2f((2.0f * LOG2E) * x);
  return 1.0f - 2.0f * __builtin_amdgcn_rcpf(t + 1.0f);
}

// zero the 4MB xchg buffer (tags must start != 1..256)
__global__ void zero_xchg(ull* __restrict__ x) {
  size_t i = ((size_t)blockIdx.x * 256 + threadIdx.x) * 4;
  x[i] = 0; x[i + 1] = 0; x[i + 2] = 0; x[i + 3] = 0;
}

// ---------------------------------------------------------------------------
// Pack W_hh[1024x256] (k 0..255) + W_ih[1024x32] (k 256..287) into bf16 frags.
// frag = ((kt*2 + cg)*8 + hu)*4 + g ; element (lane,j):
//   n = g*256 + cg*128 + hu*16 + (lane&15), k = kt*32 + (lane>>4)*8 + j
// ---------------------------------------------------------------------------
__global__ void pack_w(const float* __restrict__ Whh, const float* __restrict__ Wih,
                       short* __restrict__ wpack) {
  int tid = blockIdx.x * 256 + threadIdx.x;  // 576 frags * 64 lanes
  if (tid >= 576 * 64) return;
  int lane = tid & 63;
  int frag = tid >> 6;
  int g = frag & 3, hu = (frag >> 2) & 7, cg = (frag >> 5) & 1, kt = frag >> 6;
  int n = g * 256 + cg * 128 + hu * 16 + (lane & 15);
  int k0 = kt * 32 + (lane >> 4) * 8;
  short8 v;
#pragma unroll
  for (int j = 0; j < 8; ++j) {
    int k = k0 + j;
    float f = (k < 256) ? Whh[n * 256 + k] : Wih[n * 32 + (k - 256)];
    v[j] = f2bf(f);
  }
  *(short8*)(wpack + (size_t)frag * 512 + lane * 8) = v;
}

// W_fc[256x256] -> frags (kt 0..7, ct 0..15): n = ct*16+(lane&15).
__global__ void pack_wfc(const float* __restrict__ Wfc, short* __restrict__ wfc) {
  int tid = blockIdx.x * 256 + threadIdx.x;  // 128 frags * 64 lanes
  if (tid >= 128 * 64) return;
  int lane = tid & 63;
  int frag = tid >> 6;
  int ct = frag & 15, kt = frag >> 4;
  int n = ct * 16 + (lane & 15);
  int k0 = kt * 32 + (lane >> 4) * 8;
  short8 v;
#pragma unroll
  for (int j = 0; j < 8; ++j) v[j] = f2bf(Wfc[n * 256 + k0 + j]);
  *(short8*)(wfc + (size_t)frag * 512 + lane * 8) = v;
}

// slab word index (ull units): [parity][bt][cg][tid][word0/1]
#define SLAB(p, c) ((size_t)((((p)*NBT + bt) * 2 + (c)) * 512 + tid) * 2)

// ---------------------------------------------------------------------------
// Main kernel: grid 256; bt = blockIdx&127, cg = blockIdx>>7 (same-XCD pair).
// ---------------------------------------------------------------------------
__global__ __launch_bounds__(512, 2) void lstm_main(
    const float* __restrict__ obs, const short8* __restrict__ wpack,
    const short8* __restrict__ wfc, const float* __restrict__ b_ih,
    const float* __restrict__ b_hh, const float* __restrict__ b_fc,
    ull* __restrict__ xchg, float* __restrict__ out) {
  __shared__ __align__(16) short A[2][16 * LDSTRIDE];  // parity double-buffer
  const int tid = threadIdx.x;
  const int w = tid >> 6, lane = tid & 63;
  const int l15 = lane & 15, quad = lane >> 4;
  const int bt = blockIdx.x & 127, cg = blockIdx.x >> 7;
  const int row0 = bt * 16;
  const int xr = tid >> 5, xd = tid & 31;  // x staging: row, d
  const int kro = (cg ^ 1) * 4;            // remote ktile base
  const int klo = cg * 4;                  // local ktile base

  // zero both A buffers (h_0 = 0)
  {
    short* Az = &A[0][0];
    for (int i = tid; i < 2 * 16 * LDSTRIDE; i += 512) Az[i] = 0;
  }

  // persistent weight registers: 36 frags = 144 regs (constant indices only)
  short8 wfr[9][4];
#pragma unroll
  for (int kt = 0; kt < 9; ++kt)
#pragma unroll
    for (int g = 0; g < 4; ++g)
      wfr[kt][g] = wpack[(size_t)(((kt * 2 + cg) * 8 + w) * 4 + g) * 64 + lane];

  // fused bias per gate for this lane's hidden unit (col = cg*128+w*16+l15)
  float bias[4];
#pragma unroll
  for (int g = 0; g < 4; ++g) {
    int idx = g * 256 + cg * 128 + w * 16 + l15;
    bias[g] = b_ih[idx] + b_hh[idx];
  }

  float c4[4];
#pragma unroll
  for (int i = 0; i < 4; ++i) c4[i] = 0.f;

  __syncthreads();  // zeroing done (cold path: full barrier fine)
  A[0][xr * LDSTRIDE + 256 + xd] =
      f2bf(obs[((size_t)(row0 + xr) * 256 + 0) * 32 + xd]);
  __syncthreads();  // x_0 staged

// 4 MFMAs (all gates) for one compile-time ktile (wfr index must be constant)
#define MFK(KT)                                                                \
  {                                                                            \
    const short8 a_ =                                                          \
        *(const short8*)&Acur[l15 * LDSTRIDE + (KT)*32 + quad * 8];            \
    acc[0] = __builtin_amdgcn_mfma_f32_16x16x32_bf16(a_, wfr[KT][0], acc[0],   \
                                                     0, 0, 0);                 \
    acc[1] = __builtin_amdgcn_mfma_f32_16x16x32_bf16(a_, wfr[KT][1], acc[1],   \
                                                     0, 0, 0);                 \
    acc[2] = __builtin_amdgcn_mfma_f32_16x16x32_bf16(a_, wfr[KT][2], acc[2],   \
                                                     0, 0, 0);                 \
    acc[3] = __builtin_amdgcn_mfma_f32_16x16x32_bf16(a_, wfr[KT][3], acc[3],   \
                                                     0, 0, 0);                 \
  }

  for (int t = 0; t < 256; ++t) {
    const int p = t & 1;
    short* __restrict__ Acur = &A[p][0];
    short* __restrict__ Anx = &A[p ^ 1][0];
    const int tn = (t < 255) ? (t + 1) : 255;
    // prefetch x_{t+1} (consumed at phase 6; stays in flight across barriers)
    const float xv = obs[((size_t)(row0 + xr) * 256 + tn) * 32 + xd];

    // early-issue sibling slab loads (latency overlaps local GEMM)
    const ull* __restrict__ ss = xchg + SLAB(p, cg ^ 1);
    ull s0 = 0, s1 = 0;
    if (t > 0) {
      s0 = __hip_atomic_load(&ss[0], __ATOMIC_RELAXED, __HIP_MEMORY_SCOPE_AGENT);
      s1 = __hip_atomic_load(&ss[1], __ATOMIC_RELAXED, __HIP_MEMORY_SCOPE_AGENT);
    }

    // phase 1: LOCAL GEMM (own h-half + x) -- needs nothing from sibling
    f32x4 acc[4];
#pragma unroll
    for (int g = 0; g < 4; ++g)
      acc[g] = (f32x4){bias[g], bias[g], bias[g], bias[g]};
    if (cg == 0) { MFK(0) MFK(1) MFK(2) MFK(3) }
    else         { MFK(4) MFK(5) MFK(6) MFK(7) }
    MFK(8)  // x ktile

    // phase 2: tag-check / poll sibling h_t, scatter into Acur sib-half
    if (t > 0) {
      const ull tg = (ull)t;
      while ((s0 >> 48) != tg || (s1 >> 48) != tg) {
        s0 = __hip_atomic_load(&ss[0], __ATOMIC_RELAXED, __HIP_MEMORY_SCOPE_AGENT);
        s1 = __hip_atomic_load(&ss[1], __ATOMIC_RELAXED, __HIP_MEMORY_SCOPE_AGENT);
      }
      const int scol = kro * 32 + w * 16 + l15;
      Acur[(quad * 4 + 0) * LDSTRIDE + scol] = (short)(uint16_t)s0;
      Acur[(quad * 4 + 1) * LDSTRIDE + scol] = (short)(uint16_t)(s0 >> 16);
      Acur[(quad * 4 + 2) * LDSTRIDE + scol] = (short)(uint16_t)s1;
      Acur[(quad * 4 + 3) * LDSTRIDE + scol] = (short)(uint16_t)(s1 >> 16);
    }
    // phase 3: sib-half visible to all waves -- LDS-only visibility needed,
    // so do NOT drain vmcnt (slab store / obs prefetch stay in flight).
    BARRIER_LGKM();

    // phase 4: REMOTE GEMM (sibling h-half)
    if (cg == 0) { MFK(4) MFK(5) MFK(6) MFK(7) }
    else         { MFK(0) MFK(1) MFK(2) MFK(3) }

    // phase 5: gates
    short hb[4];
#pragma unroll
    for (int reg = 0; reg < 4; ++reg) {
      float iv = sigmoidf_(acc[0][reg]);
      float fv = sigmoidf_(acc[1][reg]);
      float gv = tanhf_(acc[2][reg]);
      float ov = sigmoidf_(acc[3][reg]);
      float cc = fv * c4[reg] + iv * gv;
      c4[reg] = cc;
      hb[reg] = f2bf(ov * tanhf_(cc));
    }

    // phase 6: tagged slab store (tag t+1) FIRST, then LDS writes
    {
      const ull tg1 = (ull)(t + 1) << 48;
      ull* __restrict__ ds = xchg + SLAB((t + 1) & 1, cg);
      __hip_atomic_store(&ds[0],
                         tg1 | ((ull)(uint16_t)hb[1] << 16) | (ull)(uint16_t)hb[0],
                         __ATOMIC_RELAXED, __HIP_MEMORY_SCOPE_AGENT);
      __hip_atomic_store(&ds[1],
                         tg1 | ((ull)(uint16_t)hb[3] << 16) | (ull)(uint16_t)hb[2],
                         __ATOMIC_RELAXED, __HIP_MEMORY_SCOPE_AGENT);
    }
    {
      const int ocol = klo * 32 + w * 16 + l15;
#pragma unroll
      for (int reg = 0; reg < 4; ++reg)
        Anx[(quad * 4 + reg) * LDSTRIDE + ocol] = hb[reg];
      Anx[xr * LDSTRIDE + 256 + xd] = f2bf(xv);
    }
    // phase 7: own-half h_{t+1} + x_{t+1} visible -- again LDS-only; the
    // slab store's L3 ack must NOT gate the next step (that was R6's stall).
    BARRIER_LGKM();
  }
#undef MFK

  // ---- final exchange: complete h_256 (parity 0, tag 256) for the FC ----
  {
    const ull* __restrict__ ss = xchg + SLAB(0, cg ^ 1);
    ull s0 = __hip_atomic_load(&ss[0], __ATOMIC_RELAXED, __HIP_MEMORY_SCOPE_AGENT);
    ull s1 = __hip_atomic_load(&ss[1], __ATOMIC_RELAXED, __HIP_MEMORY_SCOPE_AGENT);
    while ((s0 >> 48) != 256ull || (s1 >> 48) != 256ull) {
      s0 = __hip_atomic_load(&ss[0], __ATOMIC_RELAXED, __HIP_MEMORY_SCOPE_AGENT);
      s1 = __hip_atomic_load(&ss[1], __ATOMIC_RELAXED, __HIP_MEMORY_SCOPE_AGENT);
    }
    const int scol = kro * 32 + w * 16 + l15;
    A[0][(quad * 4 + 0) * LDSTRIDE + scol] = (short)(uint16_t)s0;
    A[0][(quad * 4 + 1) * LDSTRIDE + scol] = (short)(uint16_t)(s0 >> 16);
    A[0][(quad * 4 + 2) * LDSTRIDE + scol] = (short)(uint16_t)s1;
    A[0][(quad * 4 + 3) * LDSTRIDE + scol] = (short)(uint16_t)(s1 >> 16);
  }
  __syncthreads();  // cold path: full barrier fine

  // FC epilogue: wave w -> out rows bt*16..+16, cols (cg*8+w)*16..+16
  {
    const int ct = cg * 8 + w;
    const int col = ct * 16 + l15;
    const float bv = b_fc[col];
    f32x4 ao = (f32x4){0.f, 0.f, 0.f, 0.f};
#pragma unroll
    for (int kt = 0; kt < 8; ++kt) {
      const short8 a = *(const short8*)&A[0][l15 * LDSTRIDE + kt * 32 + quad * 8];
      const short8 b = wfc[(size_t)(kt * 16 + ct) * 64 + lane];
      ao = __builtin_amdgcn_mfma_f32_16x16x32_bf16(a, b, ao, 0, 0, 0);
    }
#pragma unroll
    for (int reg = 0; reg < 4; ++reg) {
      const int row = row0 + quad * 4 + reg;
      out[(size_t)row * 256 + col] = ao[reg] + bv;
    }
  }
}

extern "C" void kernel_launch(void* const* d_in, const int* in_sizes, int n_in,
                              void* d_out, int out_size, void* d_ws, size_t ws_size,
                              hipStream_t stream) {
  const float* obs  = (const float*)d_in[0];   // [2048,256,32]
  const float* W_ih = (const float*)d_in[1];   // [1024,32]
  const float* W_hh = (const float*)d_in[2];   // [1024,256]
  const float* b_ih = (const float*)d_in[3];   // [1024]
  const float* b_hh = (const float*)d_in[4];   // [1024]
  const float* W_fc = (const float*)d_in[5];   // [256,256]
  const float* b_fc = (const float*)d_in[6];   // [256]
  float* out = (float*)d_out;                  // [2048,256]

  // ws layout
  short* wpack = (short*)d_ws;                       // 576*512 shorts = 576 KB
  short* wfcp  = wpack + 576 * 512;                  // 128*512 shorts = 128 KB
  ull*   xchg  = (ull*)((char*)d_ws + (576 + 128) * 1024);  // 4 MB tagged slabs

  hipLaunchKernelGGL(zero_xchg, dim3(512), dim3(256), 0, stream, xchg);
  hipLaunchKernelGGL(pack_w, dim3(144), dim3(256), 0, stream, W_hh, W_ih, wpack);
  hipLaunchKernelGGL(pack_wfc, dim3(32), dim3(256), 0, stream, W_fc, wfcp);
  hipLaunchKernelGGL(lstm_main, dim3(256), dim3(512), 0, stream, obs,
                     (const short8*)wpack, (const short8*)wfcp,
                     b_ih, b_hh, b_fc, xchg, out);
}

// Round 5
// 744.863 us; speedup vs baseline: 4.0017x; 1.0390x over previous
//
#include <hip/hip_runtime.h>
#include <stdint.h>

// ============================================================================
// LSTM (B=2048,T=256,D=32,H=256) + FC(256) on gfx950.
// R9 = R8 + FORCED register residency of the weight fragments (single change).
// R8 post-mortem: VGPR_Count=116 < 144 (the weight frags alone) proves the
// "persistent" weights were never in registers -- LLVM rematerializes the
// __restrict__ const global loads inside the t-loop instead of keeping them
// live (R7's failure mode, milder: the 288KB/CU slice is L2-resident so it
// never showed in FETCH_SIZE). Every step re-streamed weights from L2 and
// the MFMA clusters stalled on ~200cy L2 latency -- this, not barrier
// drains, is why R8's lgkm-only barriers were a null result.
// Fix: after loading, pass each wfr[kt][g] through asm("" : "+v"(...)).
// The asm redefines the value => rematerialization is impossible; with
// __launch_bounds__(512,2) the 256-VGPR/wave budget fits 144 weight regs +
// acc + temps (~210). Weight slice per CU (288KB) fits ONLY the RF (512KB);
// LDS (160KB) cannot hold it -- registers are structurally the right home.
// R6 recap (unchanged): 256 blocks = 128 batch-tiles x 2 col-groups (pair
// b <-> b+128, same XCD), 512 thr (8 waves), 1 block/CU. Wave w owns hidden
// units cg*128+w*16..+16, all 4 gates. GEMM split local (own h-half + x) /
// remote (sibling half). Exchange: two 8B relaxed agent atomics per lane,
// step tag in bits 63:48 (|h|<1 -> no aliasing; parity double-buffer +
// recurrence dep = WAR-safe). lgkm-only barriers in the hot loop.
// MFMA layouts (learn_hip verified): A[m=lane&15][k=(lane>>4)*8+j],
// B^T same, C/D: col=lane&15, row=(lane>>4)*4+reg.
// ============================================================================

typedef __attribute__((ext_vector_type(8))) short short8;
typedef __attribute__((ext_vector_type(4))) float f32x4;
typedef unsigned long long ull;

#define LDSTRIDE 296  // 288 K-cols + 8 pad shorts
#define NBT 128       // batch tiles

// lgkm-only barrier: LDS visibility across waves WITHOUT draining VMEM.
#define BARRIER_LGKM() \
  asm volatile("s_waitcnt lgkmcnt(0)\n\ts_barrier" ::: "memory")

__device__ __forceinline__ short f2bf(float f) {
  uint32_t u = __builtin_bit_cast(uint32_t, f);
  u = (u + 0x7FFFu + ((u >> 16) & 1u)) >> 16;  // RNE
  return (short)(uint16_t)u;
}

#define LOG2E 1.4426950408889634f
__device__ __forceinline__ float sigmoidf_(float x) {
  return __builtin_amdgcn_rcpf(1.0f + __builtin_amdgcn_exp2f(-LOG2E * x));
}
__device__ __forceinline__ float tanhf_(float x) {
  float t = __builtin_amdgcn_exp2f((2.0f * LOG2E) * x);
  return 1.0f - 2.0f * __builtin_amdgcn_rcpf(t + 1.0f);
}

// zero the 4MB xchg buffer (tags must start != 1..256)
__global__ void zero_xchg(ull* __restrict__ x) {
  size_t i = ((size_t)blockIdx.x * 256 + threadIdx.x) * 4;
  x[i] = 0; x[i + 1] = 0; x[i + 2] = 0; x[i + 3] = 0;
}

// ---------------------------------------------------------------------------
// Pack W_hh[1024x256] (k 0..255) + W_ih[1024x32] (k 256..287) into bf16 frags.
// frag = ((kt*2 + cg)*8 + hu)*4 + g ; element (lane,j):
//   n = g*256 + cg*128 + hu*16 + (lane&15), k = kt*32 + (lane>>4)*8 + j
// ---------------------------------------------------------------------------
__global__ void pack_w(const float* __restrict__ Whh, const float* __restrict__ Wih,
                       short* __restrict__ wpack) {
  int tid = blockIdx.x * 256 + threadIdx.x;  // 576 frags * 64 lanes
  if (tid >= 576 * 64) return;
  int lane = tid & 63;
  int frag = tid >> 6;
  int g = frag & 3, hu = (frag >> 2) & 7, cg = (frag >> 5) & 1, kt = frag >> 6;
  int n = g * 256 + cg * 128 + hu * 16 + (lane & 15);
  int k0 = kt * 32 + (lane >> 4) * 8;
  short8 v;
#pragma unroll
  for (int j = 0; j < 8; ++j) {
    int k = k0 + j;
    float f = (k < 256) ? Whh[n * 256 + k] : Wih[n * 32 + (k - 256)];
    v[j] = f2bf(f);
  }
  *(short8*)(wpack + (size_t)frag * 512 + lane * 8) = v;
}

// W_fc[256x256] -> frags (kt 0..7, ct 0..15): n = ct*16+(lane&15).
__global__ void pack_wfc(const float* __restrict__ Wfc, short* __restrict__ wfc) {
  int tid = blockIdx.x * 256 + threadIdx.x;  // 128 frags * 64 lanes
  if (tid >= 128 * 64) return;
  int lane = tid & 63;
  int frag = tid >> 6;
  int ct = frag & 15, kt = frag >> 4;
  int n = ct * 16 + (lane & 15);
  int k0 = kt * 32 + (lane >> 4) * 8;
  short8 v;
#pragma unroll
  for (int j = 0; j < 8; ++j) v[j] = f2bf(Wfc[n * 256 + k0 + j]);
  *(short8*)(wfc + (size_t)frag * 512 + lane * 8) = v;
}

// slab word index (ull units): [parity][bt][cg][tid][word0/1]
#define SLAB(p, c) ((size_t)((((p)*NBT + bt) * 2 + (c)) * 512 + tid) * 2)

// ---------------------------------------------------------------------------
// Main kernel: grid 256; bt = blockIdx&127, cg = blockIdx>>7 (same-XCD pair).
// ---------------------------------------------------------------------------
__global__ __launch_bounds__(512, 2) void lstm_main(
    const float* __restrict__ obs, const short8* __restrict__ wpack,
    const short8* __restrict__ wfc, const float* __restrict__ b_ih,
    const float* __restrict__ b_hh, const float* __restrict__ b_fc,
    ull* __restrict__ xchg, float* __restrict__ out) {
  __shared__ __align__(16) short A[2][16 * LDSTRIDE];  // parity double-buffer
  const int tid = threadIdx.x;
  const int w = tid >> 6, lane = tid & 63;
  const int l15 = lane & 15, quad = lane >> 4;
  const int bt = blockIdx.x & 127, cg = blockIdx.x >> 7;
  const int row0 = bt * 16;
  const int xr = tid >> 5, xd = tid & 31;  // x staging: row, d
  const int kro = (cg ^ 1) * 4;            // remote ktile base
  const int klo = cg * 4;                  // local ktile base

  // zero both A buffers (h_0 = 0)
  {
    short* Az = &A[0][0];
    for (int i = tid; i < 2 * 16 * LDSTRIDE; i += 512) Az[i] = 0;
  }

  // persistent weight registers: 36 frags = 144 VGPRs.
  short8 wfr[9][4];
#pragma unroll
  for (int kt = 0; kt < 9; ++kt)
#pragma unroll
    for (int g = 0; g < 4; ++g)
      wfr[kt][g] = wpack[(size_t)(((kt * 2 + cg) * 8 + w) * 4 + g) * 64 + lane];

  // R9 PIN: redefine each frag through empty asm so LLVM cannot rematerialize
  // the global load inside the t-loop (the MFMA operand becomes an asm
  // result). This is what actually makes them persistent (VGPR_Count must
  // report >= ~195 -- if it reads ~116 the pin failed).
#pragma unroll
  for (int kt = 0; kt < 9; ++kt)
#pragma unroll
    for (int g = 0; g < 4; ++g)
      asm volatile("" : "+v"(wfr[kt][g]));

  // fused bias per gate for this lane's hidden unit (col = cg*128+w*16+l15)
  float bias[4];
#pragma unroll
  for (int g = 0; g < 4; ++g) {
    int idx = g * 256 + cg * 128 + w * 16 + l15;
    bias[g] = b_ih[idx] + b_hh[idx];
  }

  float c4[4];
#pragma unroll
  for (int i = 0; i < 4; ++i) c4[i] = 0.f;

  __syncthreads();  // zeroing done (cold path: full barrier fine)
  A[0][xr * LDSTRIDE + 256 + xd] =
      f2bf(obs[((size_t)(row0 + xr) * 256 + 0) * 32 + xd]);
  __syncthreads();  // x_0 staged

// 4 MFMAs (all gates) for one compile-time ktile (wfr index must be constant)
#define MFK(KT)                                                                \
  {                                                                            \
    const short8 a_ =                                                          \
        *(const short8*)&Acur[l15 * LDSTRIDE + (KT)*32 + quad * 8];            \
    acc[0] = __builtin_amdgcn_mfma_f32_16x16x32_bf16(a_, wfr[KT][0], acc[0],   \
                                                     0, 0, 0);                 \
    acc[1] = __builtin_amdgcn_mfma_f32_16x16x32_bf16(a_, wfr[KT][1], acc[1],   \
                                                     0, 0, 0);                 \
    acc[2] = __builtin_amdgcn_mfma_f32_16x16x32_bf16(a_, wfr[KT][2], acc[2],   \
                                                     0, 0, 0);                 \
    acc[3] = __builtin_amdgcn_mfma_f32_16x16x32_bf16(a_, wfr[KT][3], acc[3],   \
                                                     0, 0, 0);                 \
  }

  for (int t = 0; t < 256; ++t) {
    const int p = t & 1;
    short* __restrict__ Acur = &A[p][0];
    short* __restrict__ Anx = &A[p ^ 1][0];
    const int tn = (t < 255) ? (t + 1) : 255;
    // prefetch x_{t+1} (consumed at phase 6; stays in flight across barriers)
    const float xv = obs[((size_t)(row0 + xr) * 256 + tn) * 32 + xd];

    // early-issue sibling slab loads (latency overlaps local GEMM)
    const ull* __restrict__ ss = xchg + SLAB(p, cg ^ 1);
    ull s0 = 0, s1 = 0;
    if (t > 0) {
      s0 = __hip_atomic_load(&ss[0], __ATOMIC_RELAXED, __HIP_MEMORY_SCOPE_AGENT);
      s1 = __hip_atomic_load(&ss[1], __ATOMIC_RELAXED, __HIP_MEMORY_SCOPE_AGENT);
    }

    // phase 1: LOCAL GEMM (own h-half + x) -- needs nothing from sibling
    f32x4 acc[4];
#pragma unroll
    for (int g = 0; g < 4; ++g)
      acc[g] = (f32x4){bias[g], bias[g], bias[g], bias[g]};
    if (cg == 0) { MFK(0) MFK(1) MFK(2) MFK(3) }
    else         { MFK(4) MFK(5) MFK(6) MFK(7) }
    MFK(8)  // x ktile

    // phase 2: tag-check / poll sibling h_t, scatter into Acur sib-half
    if (t > 0) {
      const ull tg = (ull)t;
      while ((s0 >> 48) != tg || (s1 >> 48) != tg) {
        s0 = __hip_atomic_load(&ss[0], __ATOMIC_RELAXED, __HIP_MEMORY_SCOPE_AGENT);
        s1 = __hip_atomic_load(&ss[1], __ATOMIC_RELAXED, __HIP_MEMORY_SCOPE_AGENT);
      }
      const int scol = kro * 32 + w * 16 + l15;
      Acur[(quad * 4 + 0) * LDSTRIDE + scol] = (short)(uint16_t)s0;
      Acur[(quad * 4 + 1) * LDSTRIDE + scol] = (short)(uint16_t)(s0 >> 16);
      Acur[(quad * 4 + 2) * LDSTRIDE + scol] = (short)(uint16_t)s1;
      Acur[(quad * 4 + 3) * LDSTRIDE + scol] = (short)(uint16_t)(s1 >> 16);
    }
    // phase 3: sib-half visible to all waves (LDS-only visibility)
    BARRIER_LGKM();

    // phase 4: REMOTE GEMM (sibling h-half)
    if (cg == 0) { MFK(4) MFK(5) MFK(6) MFK(7) }
    else         { MFK(0) MFK(1) MFK(2) MFK(3) }

    // phase 5: gates
    short hb[4];
#pragma unroll
    for (int reg = 0; reg < 4; ++reg) {
      float iv = sigmoidf_(acc[0][reg]);
      float fv = sigmoidf_(acc[1][reg]);
      float gv = tanhf_(acc[2][reg]);
      float ov = sigmoidf_(acc[3][reg]);
      float cc = fv * c4[reg] + iv * gv;
      c4[reg] = cc;
      hb[reg] = f2bf(ov * tanhf_(cc));
    }

    // phase 6: tagged slab store (tag t+1) FIRST, then LDS writes
    {
      const ull tg1 = (ull)(t + 1) << 48;
      ull* __restrict__ ds = xchg + SLAB((t + 1) & 1, cg);
      __hip_atomic_store(&ds[0],
                         tg1 | ((ull)(uint16_t)hb[1] << 16) | (ull)(uint16_t)hb[0],
                         __ATOMIC_RELAXED, __HIP_MEMORY_SCOPE_AGENT);
      __hip_atomic_store(&ds[1],
                         tg1 | ((ull)(uint16_t)hb[3] << 16) | (ull)(uint16_t)hb[2],
                         __ATOMIC_RELAXED, __HIP_MEMORY_SCOPE_AGENT);
    }
    {
      const int ocol = klo * 32 + w * 16 + l15;
#pragma unroll
      for (int reg = 0; reg < 4; ++reg)
        Anx[(quad * 4 + reg) * LDSTRIDE + ocol] = hb[reg];
      Anx[xr * LDSTRIDE + 256 + xd] = f2bf(xv);
    }
    // phase 7: own-half h_{t+1} + x_{t+1} visible (LDS-only)
    BARRIER_LGKM();
  }
#undef MFK

  // ---- final exchange: complete h_256 (parity 0, tag 256) for the FC ----
  {
    const ull* __restrict__ ss = xchg + SLAB(0, cg ^ 1);
    ull s0 = __hip_atomic_load(&ss[0], __ATOMIC_RELAXED, __HIP_MEMORY_SCOPE_AGENT);
    ull s1 = __hip_atomic_load(&ss[1], __ATOMIC_RELAXED, __HIP_MEMORY_SCOPE_AGENT);
    while ((s0 >> 48) != 256ull || (s1 >> 48) != 256ull) {
      s0 = __hip_atomic_load(&ss[0], __ATOMIC_RELAXED, __HIP_MEMORY_SCOPE_AGENT);
      s1 = __hip_atomic_load(&ss[1], __ATOMIC_RELAXED, __HIP_MEMORY_SCOPE_AGENT);
    }
    const int scol = kro * 32 + w * 16 + l15;
    A[0][(quad * 4 + 0) * LDSTRIDE + scol] = (short)(uint16_t)s0;
    A[0][(quad * 4 + 1) * LDSTRIDE + scol] = (short)(uint16_t)(s0 >> 16);
    A[0][(quad * 4 + 2) * LDSTRIDE + scol] = (short)(uint16_t)s1;
    A[0][(quad * 4 + 3) * LDSTRIDE + scol] = (short)(uint16_t)(s1 >> 16);
  }
  __syncthreads();  // cold path: full barrier fine

  // FC epilogue: wave w -> out rows bt*16..+16, cols (cg*8+w)*16..+16
  {
    const int ct = cg * 8 + w;
    const int col = ct * 16 + l15;
    const float bv = b_fc[col];
    f32x4 ao = (f32x4){0.f, 0.f, 0.f, 0.f};
#pragma unroll
    for (int kt = 0; kt < 8; ++kt) {
      const short8 a = *(const short8*)&A[0][l15 * LDSTRIDE + kt * 32 + quad * 8];
      const short8 b = wfc[(size_t)(kt * 16 + ct) * 64 + lane];
      ao = __builtin_amdgcn_mfma_f32_16x16x32_bf16(a, b, ao, 0, 0, 0);
    }
#pragma unroll
    for (int reg = 0; reg < 4; ++reg) {
      const int row = row0 + quad * 4 + reg;
      out[(size_t)row * 256 + col] = ao[reg] + bv;
    }
  }
}

extern "C" void kernel_launch(void* const* d_in, const int* in_sizes, int n_in,
                              void* d_out, int out_size, void* d_ws, size_t ws_size,
                              hipStream_t stream) {
  const float* obs  = (const float*)d_in[0];   // [2048,256,32]
  const float* W_ih = (const float*)d_in[1];   // [1024,32]
  const float* W_hh = (const float*)d_in[2];   // [1024,256]
  const float* b_ih = (const float*)d_in[3];   // [1024]
  const float* b_hh = (const float*)d_in[4];   // [1024]
  const float* W_fc = (const float*)d_in[5];   // [256,256]
  const float* b_fc = (const float*)d_in[6];   // [256]
  float* out = (float*)d_out;                  // [2048,256]

  // ws layout
  short* wpack = (short*)d_ws;                       // 576*512 shorts = 576 KB
  short* wfcp  = wpack + 576 * 512;                  // 128*512 shorts = 128 KB
  ull*   xchg  = (ull*)((char*)d_ws + (576 + 128) * 1024);  // 4 MB tagged slabs

  hipLaunchKernelGGL(zero_xchg, dim3(512), dim3(256), 0, stream, xchg);
  hipLaunchKernelGGL(pack_w, dim3(144), dim3(256), 0, stream, W_hh, W_ih, wpack);
  hipLaunchKernelGGL(pack_wfc, dim3(32), dim3(256), 0, stream, W_fc, wfcp);
  hipLaunchKernelGGL(lstm_main, dim3(256), dim3(512), 0, stream, obs,
                     (const short8*)wpack, (const short8*)wfcp,
                     b_ih, b_hh, b_fc, xchg, out);
}

// Round 6
// 557.611 us; speedup vs baseline: 5.3455x; 1.3358x over previous
//
#include <hip/hip_runtime.h>
#include <stdint.h>

// ============================================================================
// LSTM (B=2048,T=256,D=32,H=256) + FC(256) on gfx950.
// R10 = R6/R9 structure + WIDE self-validating exchange (fewer transactions).
// Diagnosis (R6=R8=R9 ~6500cy/step): VALUBusy excess => ~30 poll iterations
// per step; exchange = ~8M small 8B agent-scope transactions/step chip-wide,
// throughput-bound at the coherence point; the poll storm also delays the
// stores it waits on. Fix the wire format, keep the protocol:
//  - slab dword = payload_short | tag<<16 : EVERY dword self-validates, so a
//    single non-atomic 16B global_store_dwordx4 sc0 sc1 is safe (dword-level
//    HW atomicity; torn halves fail the tag check and retry, never accepted).
//  - consumer: ONE speculative 16B global_load_dwordx4 sc0 sc1 per thread,
//    issued at step start; s_waitcnt vmcnt(1) at the check leaves the obs
//    prefetch in flight. Retry path backs off with s_sleep(2).
//  - freshness: consumer completing step t-2 certifies slab content is
//    h_{t-2} or h_t; the 16-bit tag distinguishes them (R6 argument).
// 256 blocks = 128 batch-tiles x 2 col-groups (pair b <-> b+128, same XCD),
// 512 thr (8 waves), 1 block/CU. Wave w owns hidden units cg*128+w*16..+16,
// all 4 gates; 36 weight frags pinned resident (R9 pin kept as insurance;
// they live in the acc half of the unified RF -- VGPR_Count ~116 is arch
// regs only). GEMM split local (own h-half + x) / remote (sibling half).
// lgkm-only barriers in the hot loop (R8; vmcnt stays in flight).
// MFMA layouts (learn_hip verified): A[m=lane&15][k=(lane>>4)*8+j],
// B^T same, C/D: col=lane&15, row=(lane>>4)*4+reg.
// ============================================================================

typedef __attribute__((ext_vector_type(8))) short short8;
typedef __attribute__((ext_vector_type(4))) float f32x4;
typedef __attribute__((ext_vector_type(4))) uint32_t u32x4;
typedef unsigned long long ull;

#define LDSTRIDE 296  // 288 K-cols + 8 pad shorts
#define NBT 128       // batch tiles

// lgkm-only barrier: LDS visibility across waves WITHOUT draining VMEM.
#define BARRIER_LGKM() \
  asm volatile("s_waitcnt lgkmcnt(0)\n\ts_barrier" ::: "memory")

__device__ __forceinline__ short f2bf(float f) {
  uint32_t u = __builtin_bit_cast(uint32_t, f);
  u = (u + 0x7FFFu + ((u >> 16) & 1u)) >> 16;  // RNE
  return (short)(uint16_t)u;
}

#define LOG2E 1.4426950408889634f
__device__ __forceinline__ float sigmoidf_(float x) {
  return __builtin_amdgcn_rcpf(1.0f + __builtin_amdgcn_exp2f(-LOG2E * x));
}
__device__ __forceinline__ float tanhf_(float x) {
  float t = __builtin_amdgcn_exp2f((2.0f * LOG2E) * x);
  return 1.0f - 2.0f * __builtin_amdgcn_rcpf(t + 1.0f);
}

// 16B coherent (bypass-L1/L2, serviced at coherence point) load, wait inside.
__device__ __forceinline__ u32x4 load16_sc(const uint32_t* p) {
  u32x4 r;
  asm volatile("global_load_dwordx4 %0, %1, off sc0 sc1\n\ts_waitcnt vmcnt(0)"
               : "=v"(r)
               : "v"(p)
               : "memory");
  return r;
}
// 16B write-through store to the coherence point (non-atomic; dwords
// self-validate via embedded tags).
__device__ __forceinline__ void store16_sc(uint32_t* p, u32x4 v) {
  asm volatile("global_store_dwordx4 %0, %1, off sc0 sc1" ::"v"(p), "v"(v)
               : "memory");
}

// zero the 4MB xchg buffer (tags must start != 1..256)
__global__ void zero_xchg(ull* __restrict__ x) {
  size_t i = ((size_t)blockIdx.x * 256 + threadIdx.x) * 4;
  x[i] = 0; x[i + 1] = 0; x[i + 2] = 0; x[i + 3] = 0;
}

// ---------------------------------------------------------------------------
// Pack W_hh[1024x256] (k 0..255) + W_ih[1024x32] (k 256..287) into bf16 frags.
// frag = ((kt*2 + cg)*8 + hu)*4 + g ; element (lane,j):
//   n = g*256 + cg*128 + hu*16 + (lane&15), k = kt*32 + (lane>>4)*8 + j
// ---------------------------------------------------------------------------
__global__ void pack_w(const float* __restrict__ Whh, const float* __restrict__ Wih,
                       short* __restrict__ wpack) {
  int tid = blockIdx.x * 256 + threadIdx.x;  // 576 frags * 64 lanes
  if (tid >= 576 * 64) return;
  int lane = tid & 63;
  int frag = tid >> 6;
  int g = frag & 3, hu = (frag >> 2) & 7, cg = (frag >> 5) & 1, kt = frag >> 6;
  int n = g * 256 + cg * 128 + hu * 16 + (lane & 15);
  int k0 = kt * 32 + (lane >> 4) * 8;
  short8 v;
#pragma unroll
  for (int j = 0; j < 8; ++j) {
    int k = k0 + j;
    float f = (k < 256) ? Whh[n * 256 + k] : Wih[n * 32 + (k - 256)];
    v[j] = f2bf(f);
  }
  *(short8*)(wpack + (size_t)frag * 512 + lane * 8) = v;
}

// W_fc[256x256] -> frags (kt 0..7, ct 0..15): n = ct*16+(lane&15).
__global__ void pack_wfc(const float* __restrict__ Wfc, short* __restrict__ wfc) {
  int tid = blockIdx.x * 256 + threadIdx.x;  // 128 frags * 64 lanes
  if (tid >= 128 * 64) return;
  int lane = tid & 63;
  int frag = tid >> 6;
  int ct = frag & 15, kt = frag >> 4;
  int n = ct * 16 + (lane & 15);
  int k0 = kt * 32 + (lane >> 4) * 8;
  short8 v;
#pragma unroll
  for (int j = 0; j < 8; ++j) v[j] = f2bf(Wfc[n * 256 + k0 + j]);
  *(short8*)(wfc + (size_t)frag * 512 + lane * 8) = v;
}

// slab dword index: [parity][bt][cg][tid] x 4 dwords (16B per thread)
#define SLABD(p, c) (((((size_t)(p)) * NBT + bt) * 2 + (c)) * 512 + tid) * 4

// ---------------------------------------------------------------------------
// Main kernel: grid 256; bt = blockIdx&127, cg = blockIdx>>7 (same-XCD pair).
// ---------------------------------------------------------------------------
__global__ __launch_bounds__(512, 2) void lstm_main(
    const float* __restrict__ obs, const short8* __restrict__ wpack,
    const short8* __restrict__ wfc, const float* __restrict__ b_ih,
    const float* __restrict__ b_hh, const float* __restrict__ b_fc,
    uint32_t* __restrict__ xchg, float* __restrict__ out) {
  __shared__ __align__(16) short A[2][16 * LDSTRIDE];  // parity double-buffer
  const int tid = threadIdx.x;
  const int w = tid >> 6, lane = tid & 63;
  const int l15 = lane & 15, quad = lane >> 4;
  const int bt = blockIdx.x & 127, cg = blockIdx.x >> 7;
  const int row0 = bt * 16;
  const int xr = tid >> 5, xd = tid & 31;  // x staging: row, d
  const int kro = (cg ^ 1) * 4;            // remote ktile base
  const int klo = cg * 4;                  // local ktile base

  // zero both A buffers (h_0 = 0)
  {
    short* Az = &A[0][0];
    for (int i = tid; i < 2 * 16 * LDSTRIDE; i += 512) Az[i] = 0;
  }

  // persistent weight registers: 36 frags (live in the unified RF's acc half)
  short8 wfr[9][4];
#pragma unroll
  for (int kt = 0; kt < 9; ++kt)
#pragma unroll
    for (int g = 0; g < 4; ++g)
      wfr[kt][g] = wpack[(size_t)(((kt * 2 + cg) * 8 + w) * 4 + g) * 64 + lane];
#pragma unroll
  for (int kt = 0; kt < 9; ++kt)
#pragma unroll
    for (int g = 0; g < 4; ++g)
      asm volatile("" : "+v"(wfr[kt][g]));  // R9 pin (measured-neutral insurance)

  // fused bias per gate for this lane's hidden unit (col = cg*128+w*16+l15)
  float bias[4];
#pragma unroll
  for (int g = 0; g < 4; ++g) {
    int idx = g * 256 + cg * 128 + w * 16 + l15;
    bias[g] = b_ih[idx] + b_hh[idx];
  }

  float c4[4];
#pragma unroll
  for (int i = 0; i < 4; ++i) c4[i] = 0.f;

  __syncthreads();  // zeroing done (cold path: full barrier fine)
  A[0][xr * LDSTRIDE + 256 + xd] =
      f2bf(obs[((size_t)(row0 + xr) * 256 + 0) * 32 + xd]);
  __syncthreads();  // x_0 staged

// 4 MFMAs (all gates) for one compile-time ktile (wfr index must be constant)
#define MFK(KT)                                                                \
  {                                                                            \
    const short8 a_ =                                                          \
        *(const short8*)&Acur[l15 * LDSTRIDE + (KT)*32 + quad * 8];            \
    acc[0] = __builtin_amdgcn_mfma_f32_16x16x32_bf16(a_, wfr[KT][0], acc[0],   \
                                                     0, 0, 0);                 \
    acc[1] = __builtin_amdgcn_mfma_f32_16x16x32_bf16(a_, wfr[KT][1], acc[1],   \
                                                     0, 0, 0);                 \
    acc[2] = __builtin_amdgcn_mfma_f32_16x16x32_bf16(a_, wfr[KT][2], acc[2],   \
                                                     0, 0, 0);                 \
    acc[3] = __builtin_amdgcn_mfma_f32_16x16x32_bf16(a_, wfr[KT][3], acc[3],   \
                                                     0, 0, 0);                 \
  }

  for (int t = 0; t < 256; ++t) {
    const int p = t & 1;
    short* __restrict__ Acur = &A[p][0];
    short* __restrict__ Anx = &A[p ^ 1][0];
    const int tn = (t < 255) ? (t + 1) : 255;

    // early-issue speculative sibling slab load (ONE 16B op; latency overlaps
    // local GEMM). "memory" clobber pins the obs load AFTER this issue so
    // the vmcnt(1) below leaves exactly the obs prefetch in flight.
    const uint32_t* sa = xchg + SLABD(p, cg ^ 1);
    u32x4 sv = (u32x4){0, 0, 0, 0};
    if (t > 0)
      asm volatile("global_load_dwordx4 %0, %1, off sc0 sc1"
                   : "=v"(sv)
                   : "v"(sa)
                   : "memory");

    // obs prefetch x_{t+1} (consumed at phase 6; stays in flight)
    const float xv = obs[((size_t)(row0 + xr) * 256 + tn) * 32 + xd];

    // phase 1: LOCAL GEMM (own h-half + x) -- needs nothing from sibling
    f32x4 acc[4];
#pragma unroll
    for (int g = 0; g < 4; ++g)
      acc[g] = (f32x4){bias[g], bias[g], bias[g], bias[g]};
    if (cg == 0) { MFK(0) MFK(1) MFK(2) MFK(3) }
    else         { MFK(4) MFK(5) MFK(6) MFK(7) }
    MFK(8)  // x ktile

    // phase 2: validate tags / backoff-poll, scatter into Acur sib-half
    if (t > 0) {
      // wait for the speculative load only (obs prefetch stays outstanding);
      // "+v"(sv) ties the wait to the data so uses cannot be hoisted (rule 18)
      asm volatile("s_waitcnt vmcnt(1)" : "+v"(sv)::"memory");
      __builtin_amdgcn_sched_barrier(0);
      const uint32_t want = (uint32_t)t << 16;
      for (;;) {
        const uint32_t bad = ((sv[0] ^ want) | (sv[1] ^ want) | (sv[2] ^ want) |
                              (sv[3] ^ want)) & 0xFFFF0000u;
        if (!bad) break;
        __builtin_amdgcn_s_sleep(2);  // ~128cy backoff: kill the poll storm
        sv = load16_sc(sa);
      }
      const int scol = kro * 32 + w * 16 + l15;
      Acur[(quad * 4 + 0) * LDSTRIDE + scol] = (short)(uint16_t)sv[0];
      Acur[(quad * 4 + 1) * LDSTRIDE + scol] = (short)(uint16_t)sv[1];
      Acur[(quad * 4 + 2) * LDSTRIDE + scol] = (short)(uint16_t)sv[2];
      Acur[(quad * 4 + 3) * LDSTRIDE + scol] = (short)(uint16_t)sv[3];
    }
    // phase 3: sib-half visible to all waves (LDS-only visibility)
    BARRIER_LGKM();

    // phase 4: REMOTE GEMM (sibling h-half)
    if (cg == 0) { MFK(4) MFK(5) MFK(6) MFK(7) }
    else         { MFK(0) MFK(1) MFK(2) MFK(3) }

    // phase 5: gates
    short hb[4];
#pragma unroll
    for (int reg = 0; reg < 4; ++reg) {
      float iv = sigmoidf_(acc[0][reg]);
      float fv = sigmoidf_(acc[1][reg]);
      float gv = tanhf_(acc[2][reg]);
      float ov = sigmoidf_(acc[3][reg]);
      float cc = fv * c4[reg] + iv * gv;
      c4[reg] = cc;
      hb[reg] = f2bf(ov * tanhf_(cc));
    }

    // phase 6: ONE tagged 16B slab store (each dword self-validates), then LDS
    {
      const uint32_t tg1 = (uint32_t)(t + 1) << 16;
      uint32_t* ds = xchg + SLABD((t + 1) & 1, cg);
      u32x4 pv = (u32x4){tg1 | (uint16_t)hb[0], tg1 | (uint16_t)hb[1],
                         tg1 | (uint16_t)hb[2], tg1 | (uint16_t)hb[3]};
      store16_sc(ds, pv);
    }
    {
      const int ocol = klo * 32 + w * 16 + l15;
#pragma unroll
      for (int reg = 0; reg < 4; ++reg)
        Anx[(quad * 4 + reg) * LDSTRIDE + ocol] = hb[reg];
      Anx[xr * LDSTRIDE + 256 + xd] = f2bf(xv);
    }
    // phase 7: own-half h_{t+1} + x_{t+1} visible (LDS-only; the slab store's
    // coherence-point ack must NOT gate the next step)
    BARRIER_LGKM();
  }
#undef MFK

  // ---- final exchange: complete h_256 (parity 0, tag 256) for the FC ----
  {
    const uint32_t* sa = xchg + SLABD(0, cg ^ 1);
    const uint32_t want = 256u << 16;
    u32x4 sv = load16_sc(sa);
    for (;;) {
      const uint32_t bad = ((sv[0] ^ want) | (sv[1] ^ want) | (sv[2] ^ want) |
                            (sv[3] ^ want)) & 0xFFFF0000u;
      if (!bad) break;
      __builtin_amdgcn_s_sleep(2);
      sv = load16_sc(sa);
    }
    const int scol = kro * 32 + w * 16 + l15;
    A[0][(quad * 4 + 0) * LDSTRIDE + scol] = (short)(uint16_t)sv[0];
    A[0][(quad * 4 + 1) * LDSTRIDE + scol] = (short)(uint16_t)sv[1];
    A[0][(quad * 4 + 2) * LDSTRIDE + scol] = (short)(uint16_t)sv[2];
    A[0][(quad * 4 + 3) * LDSTRIDE + scol] = (short)(uint16_t)sv[3];
  }
  __syncthreads();  // cold path: full barrier fine

  // FC epilogue: wave w -> out rows bt*16..+16, cols (cg*8+w)*16..+16
  {
    const int ct = cg * 8 + w;
    const int col = ct * 16 + l15;
    const float bv = b_fc[col];
    f32x4 ao = (f32x4){0.f, 0.f, 0.f, 0.f};
#pragma unroll
    for (int kt = 0; kt < 8; ++kt) {
      const short8 a = *(const short8*)&A[0][l15 * LDSTRIDE + kt * 32 + quad * 8];
      const short8 b = wfc[(size_t)(kt * 16 + ct) * 64 + lane];
      ao = __builtin_amdgcn_mfma_f32_16x16x32_bf16(a, b, ao, 0, 0, 0);
    }
#pragma unroll
    for (int reg = 0; reg < 4; ++reg) {
      const int row = row0 + quad * 4 + reg;
      out[(size_t)row * 256 + col] = ao[reg] + bv;
    }
  }
}

extern "C" void kernel_launch(void* const* d_in, const int* in_sizes, int n_in,
                              void* d_out, int out_size, void* d_ws, size_t ws_size,
                              hipStream_t stream) {
  const float* obs  = (const float*)d_in[0];   // [2048,256,32]
  const float* W_ih = (const float*)d_in[1];   // [1024,32]
  const float* W_hh = (const float*)d_in[2];   // [1024,256]
  const float* b_ih = (const float*)d_in[3];   // [1024]
  const float* b_hh = (const float*)d_in[4];   // [1024]
  const float* W_fc = (const float*)d_in[5];   // [256,256]
  const float* b_fc = (const float*)d_in[6];   // [256]
  float* out = (float*)d_out;                  // [2048,256]

  // ws layout
  short*    wpack = (short*)d_ws;                      // 576*512 shorts = 576 KB
  short*    wfcp  = wpack + 576 * 512;                 // 128*512 shorts = 128 KB
  uint32_t* xchg  = (uint32_t*)((char*)d_ws + (576 + 128) * 1024);  // 4 MB slabs

  hipLaunchKernelGGL(zero_xchg, dim3(512), dim3(256), 0, stream, (ull*)xchg);
  hipLaunchKernelGGL(pack_w, dim3(144), dim3(256), 0, stream, W_hh, W_ih, wpack);
  hipLaunchKernelGGL(pack_wfc, dim3(32), dim3(256), 0, stream, W_fc, wfcp);
  hipLaunchKernelGGL(lstm_main, dim3(256), dim3(512), 0, stream, obs,
                     (const short8*)wpack, (const short8*)wfcp,
                     b_ih, b_hh, b_fc, xchg, out);
}